// Round 1
// baseline (753.155 us; speedup 1.0000x reference)
//
#include <hip/hip_runtime.h>
#include <math.h>

// Problem constants (fixed by the reference)
#define C_   4096
#define H_   256
#define V_   16000
#define SPW  32
#define NB   32    // N (batch)
#define TT   128   // T (sequence length)

// ---------------------------------------------------------------------------
// Workspace layout (float offsets). Total ~27.0M floats = ~108 MB.
// ---------------------------------------------------------------------------
static const size_t OFF_TL    = 0;                                   // C*C transition logits
static const size_t OFF_RES   = OFF_TL   + (size_t)C_ * C_;          // C*H residual out (reused 3x sequentially)
static const size_t OFF_STMP  = OFF_RES  + (size_t)C_ * H_;          // C   start pre-softmax
static const size_t OFF_START = OFF_STMP + C_;                       // C   start log-probs
static const size_t OFF_LSE1  = OFF_START + C_;                      // C
static const size_t OFF_LSE2  = OFF_LSE1 + C_;                       // C
static const size_t OFF_RMAX  = OFF_LSE2 + C_;                       // C (unsigned, encoded-float max)
static const size_t OFF_RSUM  = OFF_RMAX + C_;                       // C
static const size_t OFF_DEN   = OFF_RSUM + C_;                       // C emission row log-denominator
static const size_t OFF_LOGZ  = OFF_DEN  + C_;                       // NB (padded to 64)
static const size_t OFF_ELBO  = OFF_LOGZ + 64;                       // double accumulator (2 floats, 8B aligned)
static const size_t OFF_EWT   = OFF_ELBO + 16;                       // V*H transposed e_out_w
static const size_t OFF_L     = OFF_EWT  + (size_t)V_ * H_;          // V*SPW masked emission logits
static const size_t OFF_OBS   = OFF_L    + (size_t)V_ * SPW;         // N*T*SPW
static const size_t OFF_PHI   = OFF_OBS  + (size_t)NB * TT * SPW;    // (T-1)*N*SPW*SPW  phiT[t,n,j,i]
static const size_t OFF_ALPH  = OFF_PHI  + (size_t)(TT-1) * NB * SPW * SPW; // (T-1)*N*SPW
static const size_t OFF_BETA  = OFF_ALPH + (size_t)(TT-1) * NB * SPW;       // (T-1)*N*SPW

// Monotone float<->uint encoding for atomicMax on floats (handles negatives)
__device__ inline unsigned enc_f(float f) {
    unsigned u = __float_as_uint(f);
    return (u & 0x80000000u) ? ~u : (u | 0x80000000u);
}
__device__ inline float dec_f(unsigned k) {
    return (k & 0x80000000u) ? __uint_as_float(k ^ 0x80000000u) : __uint_as_float(~k);
}

// ---------------------------------------------------------------------------
// K0: init scatter accumulators + elbo accumulator (ws is poisoned each call)
// ---------------------------------------------------------------------------
__global__ void init_kernel(unsigned* __restrict__ rowmax, float* __restrict__ rowsum,
                            double* __restrict__ elbo_acc) {
    int i = blockIdx.x * 256 + threadIdx.x;
    if (i < C_) { rowmax[i] = 0u; rowsum[i] = 0.f; }   // key 0 < key(-inf): safe identity
    if (i == 0) *elbo_acc = 0.0;
}

// ---------------------------------------------------------------------------
// K1: residual MLP  out = relu(relu(x@w1+b1)@w2+b2) + x  over (C,H) rows.
// 16 rows/block so the H*H weights are read once per 16 rows (L2-resident).
// ---------------------------------------------------------------------------
__global__ __launch_bounds__(256) void residual_kernel(
    const float* __restrict__ x, const float* __restrict__ w1, const float* __restrict__ b1,
    const float* __restrict__ w2, const float* __restrict__ b2, float* __restrict__ out)
{
    __shared__ float xs[16][H_];
    __shared__ float hs[16][H_];
    int t  = threadIdx.x;
    int r0 = blockIdx.x * 16;
    for (int r = 0; r < 16; ++r) xs[r][t] = x[(size_t)(r0 + r) * H_ + t];
    __syncthreads();
    float acc[16];
#pragma unroll
    for (int r = 0; r < 16; ++r) acc[r] = 0.f;
    for (int k = 0; k < H_; ++k) {
        float w = w1[k * H_ + t];
#pragma unroll
        for (int r = 0; r < 16; ++r) acc[r] += xs[r][k] * w;  // xs[r][k]: LDS broadcast
    }
    float bb = b1[t];
#pragma unroll
    for (int r = 0; r < 16; ++r) hs[r][t] = fmaxf(acc[r] + bb, 0.f);
    __syncthreads();
#pragma unroll
    for (int r = 0; r < 16; ++r) acc[r] = 0.f;
    for (int k = 0; k < H_; ++k) {
        float w = w2[k * H_ + t];
#pragma unroll
        for (int r = 0; r < 16; ++r) acc[r] += hs[r][k] * w;
    }
    float b2v = b2[t];
#pragma unroll
    for (int r = 0; r < 16; ++r)
        out[(size_t)(r0 + r) * H_ + t] = fmaxf(acc[r] + b2v, 0.f) + xs[r][t];
}

// ---------------------------------------------------------------------------
// K2: start head  s[c] = dot(res[c,:], s_out_w) + s_out_b   (one wave per row)
// ---------------------------------------------------------------------------
__global__ __launch_bounds__(256) void start_head_kernel(
    const float* __restrict__ res, const float* __restrict__ sow,
    const float* __restrict__ sob, float* __restrict__ s_tmp)
{
    int wave = threadIdx.x >> 6;
    int lane = threadIdx.x & 63;
    int c = blockIdx.x * 4 + wave;
    float sum = 0.f;
    for (int k = lane; k < H_; k += 64) sum += res[(size_t)c * H_ + k] * sow[k];
#pragma unroll
    for (int off = 32; off; off >>= 1) sum += __shfl_xor(sum, off);
    if (lane == 0) s_tmp[c] = sum + sob[0];
}

// ---------------------------------------------------------------------------
// K3: log_softmax over C=4096 in one block (1024 threads, 4 elems each)
// ---------------------------------------------------------------------------
__global__ __launch_bounds__(1024) void logsoftmax_start_kernel(
    const float* __restrict__ s_tmp, float* __restrict__ out)
{
    __shared__ float red_m[16];
    __shared__ float red_s[16];
    int t = threadIdx.x;
    float v[4];
    float m = -INFINITY;
#pragma unroll
    for (int q = 0; q < 4; ++q) { v[q] = s_tmp[t + q * 1024]; m = fmaxf(m, v[q]); }
#pragma unroll
    for (int off = 32; off; off >>= 1) m = fmaxf(m, __shfl_xor(m, off));
    if ((t & 63) == 0) red_m[t >> 6] = m;
    __syncthreads();
    float M = red_m[0];
#pragma unroll
    for (int w = 1; w < 16; ++w) M = fmaxf(M, red_m[w]);
    float s = 0.f;
#pragma unroll
    for (int q = 0; q < 4; ++q) s += expf(v[q] - M);
#pragma unroll
    for (int off = 32; off; off >>= 1) s += __shfl_xor(s, off);
    if ((t & 63) == 0) red_s[t >> 6] = s;
    __syncthreads();
    float S = 0.f;
#pragma unroll
    for (int w = 0; w < 16; ++w) S += red_s[w];
    float lg = logf(S);
#pragma unroll
    for (int q = 0; q < 4; ++q) out[t + q * 1024] = (v[q] - M) - lg;
}

// ---------------------------------------------------------------------------
// K4: TL[i,j] = dot(A[i,:], B[j,:])  — fp32 NT GEMM, 64x64 tile, 4x4/thread
// ---------------------------------------------------------------------------
__global__ __launch_bounds__(256) void matmul_nt_kernel(
    const float* __restrict__ A, const float* __restrict__ B, float* __restrict__ Cmat)
{
    __shared__ __align__(16) float As[16][68];   // stride 68: 16B-aligned float4 rows
    __shared__ __align__(16) float Bs[16][68];
    int tid = threadIdx.x;
    int tx = tid & 15, ty = tid >> 4;
    int j0 = blockIdx.x * 64, i0 = blockIdx.y * 64;
    int lrow = tid >> 2;          // 0..63
    int lk   = (tid & 3) * 4;     // 0,4,8,12
    const float* Arow = A + (size_t)(i0 + lrow) * H_;
    const float* Brow = B + (size_t)(j0 + lrow) * H_;
    float acc[4][4] = {};
    for (int k0 = 0; k0 < H_; k0 += 16) {
        float4 av = *(const float4*)(Arow + k0 + lk);
        float4 bv = *(const float4*)(Brow + k0 + lk);
        __syncthreads();
        As[lk + 0][lrow] = av.x; As[lk + 1][lrow] = av.y;
        As[lk + 2][lrow] = av.z; As[lk + 3][lrow] = av.w;
        Bs[lk + 0][lrow] = bv.x; Bs[lk + 1][lrow] = bv.y;
        Bs[lk + 2][lrow] = bv.z; Bs[lk + 3][lrow] = bv.w;
        __syncthreads();
#pragma unroll
        for (int kk = 0; kk < 16; ++kk) {
            float4 a4 = *(const float4*)&As[kk][ty * 4];
            float4 b4 = *(const float4*)&Bs[kk][tx * 4];
            float aa[4] = {a4.x, a4.y, a4.z, a4.w};
            float bb[4] = {b4.x, b4.y, b4.z, b4.w};
#pragma unroll
            for (int u = 0; u < 4; ++u)
#pragma unroll
                for (int w = 0; w < 4; ++w) acc[u][w] += aa[u] * bb[w];
        }
    }
#pragma unroll
    for (int u = 0; u < 4; ++u) {
        float4 o = make_float4(acc[u][0], acc[u][1], acc[u][2], acc[u][3]);
        *(float4*)(Cmat + (size_t)(i0 + ty * 4 + u) * C_ + j0 + tx * 4) = o;
    }
}

// ---------------------------------------------------------------------------
// K5: per-row online logsumexp over C columns (optionally minus sub[i])
// ---------------------------------------------------------------------------
__global__ __launch_bounds__(256) void row_lse_kernel(
    const float* __restrict__ TL, const float* __restrict__ sub,
    float* __restrict__ out_lse, int use_sub)
{
    int i = blockIdx.x;
    int t = threadIdx.x;
    float subv = use_sub ? sub[i] : 0.f;
    const float* row = TL + (size_t)i * C_;
    float m = -INFINITY, s = 0.f;
    for (int j = t; j < C_; j += 256) {
        float x = row[j] - subv;
        float nm = fmaxf(m, x);
        s = s * expf(m - nm) + expf(x - nm);
        m = nm;
    }
#pragma unroll
    for (int off = 32; off; off >>= 1) {
        float om = __shfl_xor(m, off);
        float os = __shfl_xor(s, off);
        float nm = fmaxf(m, om);
        s = s * expf(m - nm) + os * expf(om - nm);
        m = nm;
    }
    __shared__ float sm[4], ss[4];
    if ((t & 63) == 0) { sm[t >> 6] = m; ss[t >> 6] = s; }
    __syncthreads();
    if (t == 0) {
        float M = sm[0], S = ss[0];
#pragma unroll
        for (int w = 1; w < 4; ++w) {
            float nm = fmaxf(M, sm[w]);
            S = S * expf(M - nm) + ss[w] * expf(sm[w] - nm);
            M = nm;
        }
        out_lse[i] = M + logf(S);
    }
}

// ---------------------------------------------------------------------------
// K6: transpose e_out_w (H,V) -> ewT (V,H)
// ---------------------------------------------------------------------------
__global__ __launch_bounds__(256) void transpose_kernel(
    const float* __restrict__ W, float* __restrict__ WT)
{
    __shared__ float tile[32][33];
    int tx = threadIdx.x & 31, ty = threadIdx.x >> 5;   // ty 0..7
    int v0 = blockIdx.x * 32, h0 = blockIdx.y * 32;
#pragma unroll
    for (int q = 0; q < 4; ++q)
        tile[ty + 8 * q][tx] = W[(size_t)(h0 + ty + 8 * q) * V_ + v0 + tx];
    __syncthreads();
#pragma unroll
    for (int q = 0; q < 4; ++q)
        WT[(size_t)(v0 + ty + 8 * q) * H_ + h0 + tx] = tile[tx][ty + 8 * q];
}

// ---------------------------------------------------------------------------
// K7: masked emission logits  L[v,k] = dot(res_pre[w2s[v,k],:], ewT[v,:]) + eob[v]
// One block per v; 8 lanes per (v,k) dot.
// ---------------------------------------------------------------------------
__global__ __launch_bounds__(256) void em_logits_kernel(
    const float* __restrict__ res_pre, const float* __restrict__ ewT,
    const float* __restrict__ eob, const int* __restrict__ w2s, float* __restrict__ L)
{
    int v = blockIdx.x;
    __shared__ float wv[H_];
    wv[threadIdx.x] = ewT[(size_t)v * H_ + threadIdx.x];
    __syncthreads();
    int g = threadIdx.x >> 3;   // k = 0..31
    int l = threadIdx.x & 7;
    int c = w2s[v * SPW + g];
    const float* row = res_pre + (size_t)c * H_;
    float sum = 0.f;
#pragma unroll
    for (int m = 0; m < 32; ++m) { int idx = l + m * 8; sum += row[idx] * wv[idx]; }
    sum += __shfl_xor(sum, 1);
    sum += __shfl_xor(sum, 2);
    sum += __shfl_xor(sum, 4);
    if (l == 0) L[v * SPW + g] = sum + eob[v];
}

// ---------------------------------------------------------------------------
// K8/K9: scatter per-state max, then sum(exp(x-max)), deduping repeated
// states within a word's row (the boolean mask counts each (c,v) once).
// ---------------------------------------------------------------------------
__global__ __launch_bounds__(256) void row_max_kernel(
    const int* __restrict__ w2s, const float* __restrict__ L, unsigned* __restrict__ rowmax)
{
    __shared__ int st[8][32];
    int vl = threadIdx.x >> 5, k = threadIdx.x & 31;
    int v = blockIdx.x * 8 + vl;
    st[vl][k] = w2s[v * SPW + k];
    __syncthreads();
    int c = st[vl][k];
    bool dup = false;
    for (int kp = 0; kp < k; ++kp) if (st[vl][kp] == c) { dup = true; break; }
    if (!dup) atomicMax(&rowmax[c], enc_f(L[v * SPW + k]));
}

__global__ __launch_bounds__(256) void row_sum_kernel(
    const int* __restrict__ w2s, const float* __restrict__ L,
    const unsigned* __restrict__ rowmax, float* __restrict__ rowsum)
{
    __shared__ int st[8][32];
    int vl = threadIdx.x >> 5, k = threadIdx.x & 31;
    int v = blockIdx.x * 8 + vl;
    st[vl][k] = w2s[v * SPW + k];
    __syncthreads();
    int c = st[vl][k];
    bool dup = false;
    for (int kp = 0; kp < k; ++kp) if (st[vl][kp] == c) { dup = true; break; }
    if (!dup) atomicAdd(&rowsum[c], expf(L[v * SPW + k] - dec_f(rowmax[c])));
}

__global__ void denom_kernel(const unsigned* __restrict__ rowmax,
                             const float* __restrict__ rowsum, float* __restrict__ denom)
{
    int c = blockIdx.x * 256 + threadIdx.x;
    if (c >= C_) return;
    unsigned k = rowmax[c];
    denom[c] = (k == 0u) ? -INFINITY : (dec_f(k) + logf(rowsum[c]));
}

// ---------------------------------------------------------------------------
// K11: obs[n,t,k] = L[text[n,t],k] - denom[w2s[text[n,t],k]]
// ---------------------------------------------------------------------------
__global__ void obs_kernel(const int* __restrict__ text, const int* __restrict__ w2s,
                           const float* __restrict__ L, const float* __restrict__ denom,
                           float* __restrict__ obs)
{
    int idx = blockIdx.x * 256 + threadIdx.x;
    if (idx >= NB * TT * SPW) return;
    int k = idx & 31;
    int nt = idx >> 5;
    int v = text[nt];
    int c = w2s[v * SPW + k];
    obs[idx] = L[v * SPW + k] - denom[c];
}

// ---------------------------------------------------------------------------
// K12: phiT[t,n,j,i] = TL[ci,cj] - lse1[ci] - lse2[ci] + obs[n,t+1,j]
//                      + (t==0 ? start[ci] + obs[n,0,i] : 0)
// ---------------------------------------------------------------------------
__global__ __launch_bounds__(256) void phi_kernel(
    const float* __restrict__ TL, const float* __restrict__ lse1, const float* __restrict__ lse2,
    const float* __restrict__ obs, const float* __restrict__ start_log,
    const int* __restrict__ text, const int* __restrict__ w2s, float* __restrict__ phiT)
{
    int t = blockIdx.x / NB;
    int n = blockIdx.x - t * NB;
    __shared__ int c_i[32], c_j[32];
    __shared__ float addi[32], obsj[32];
    int tid = threadIdx.x;
    int v0 = text[n * TT + t], v1 = text[n * TT + t + 1];
    if (tid < 32) {
        int ci = w2s[v0 * SPW + tid];
        c_i[tid] = ci;
        float a = -lse1[ci] - lse2[ci];
        if (t == 0) a += start_log[ci] + obs[(n * TT + 0) * SPW + tid];
        addi[tid] = a;
    } else if (tid < 64) {
        int k = tid - 32;
        c_j[k] = w2s[v1 * SPW + k];
        obsj[k] = obs[(n * TT + t + 1) * SPW + k];
    }
    __syncthreads();
    size_t base = (size_t)(t * NB + n) * (SPW * SPW);
#pragma unroll
    for (int e = tid; e < SPW * SPW; e += 256) {
        int j = e >> 5, i = e & 31;
        phiT[base + e] = TL[(size_t)c_i[i] * C_ + c_j[j]] + addi[i] + obsj[j];
    }
}

// ---------------------------------------------------------------------------
// K13: forward + backward scans (blocks 0..31 fwd, 32..63 bwd, concurrent).
// 1024 threads: outer index a = tid>>5, reduction index r = tid&31.
// One-step phi prefetch hides the per-step global load latency.
// ---------------------------------------------------------------------------
__global__ __launch_bounds__(1024) void scan_kernel(
    const float* __restrict__ phiT, float* __restrict__ alphas_pre,
    float* __restrict__ betas_next, float* __restrict__ logZ, float* __restrict__ out)
{
    bool bwd = blockIdx.x >= NB;
    int n = blockIdx.x & (NB - 1);
    int tid = threadIdx.x;
    int a = tid >> 5, r = tid & 31;
    __shared__ float carry[32];
    if (tid < 32) carry[tid] = 0.f;
    __syncthreads();

    if (!bwd) {
        float pnext = phiT[(size_t)(0 * NB + n) * 1024 + a * 32 + r];
        for (int t = 0; t < TT - 1; ++t) {
            float cr = carry[r];
            float cold = (tid < 32) ? carry[tid] : 0.f;
            float p = pnext + cr;
            if (t + 1 < TT - 1)
                pnext = phiT[(size_t)((t + 1) * NB + n) * 1024 + a * 32 + r];
            float m = p;
#pragma unroll
            for (int off = 16; off; off >>= 1) m = fmaxf(m, __shfl_xor(m, off));
            float s = expf(p - m);
#pragma unroll
            for (int off = 16; off; off >>= 1) s += __shfl_xor(s, off);
            float nv = m + logf(s);
            if (tid < 32) alphas_pre[((size_t)t * NB + n) * SPW + tid] = cold;
            __syncthreads();
            if (r == 0) carry[a] = nv;
            __syncthreads();
        }
        // logZ + log_softmax(alpha_T) outputs
        if (tid < 32) {
            float x = carry[tid];
            float m = x;
#pragma unroll
            for (int off = 16; off; off >>= 1) m = fmaxf(m, __shfl_xor(m, off));
            float s = expf(x - m);
#pragma unroll
            for (int off = 16; off; off >>= 1) s += __shfl_xor(s, off);
            float lg = logf(s);
            if (tid == 0) logZ[n] = m + lg;
            out[2 + n * 32 + tid] = (x - m) - lg;
        }
    } else {
        float pnext = phiT[(size_t)((TT - 2) * NB + n) * 1024 + r * 32 + a];
        for (int t = TT - 2; t >= 0; --t) {
            float cr = carry[r];
            float cold = (tid < 32) ? carry[tid] : 0.f;
            float p = pnext + cr;
            if (t > 0)
                pnext = phiT[(size_t)((t - 1) * NB + n) * 1024 + r * 32 + a];
            float m = p;
#pragma unroll
            for (int off = 16; off; off >>= 1) m = fmaxf(m, __shfl_xor(m, off));
            float s = expf(p - m);
#pragma unroll
            for (int off = 16; off; off >>= 1) s += __shfl_xor(s, off);
            float nv = m + logf(s);
            if (tid < 32) betas_next[((size_t)t * NB + n) * SPW + tid] = cold;
            __syncthreads();
            if (r == 0) carry[a] = nv;
            __syncthreads();
        }
    }
}

// ---------------------------------------------------------------------------
// K14: elbo = sum exp(alphas_pre[i] + phi + betas_next[j] - logZ) * phi
// fp32 elementwise (matches reference), double accumulation (4M terms).
// ---------------------------------------------------------------------------
__global__ __launch_bounds__(256) void elbo_kernel(
    const float* __restrict__ phiT, const float* __restrict__ alphas_pre,
    const float* __restrict__ betas_next, const float* __restrict__ logZ,
    double* __restrict__ elbo_acc)
{
    int t = blockIdx.x / NB;
    int n = blockIdx.x - t * NB;
    int tid = threadIdx.x;
    __shared__ float ap[32], bn[32];
    if (tid < 32) ap[tid] = alphas_pre[((size_t)t * NB + n) * SPW + tid];
    else if (tid < 64) bn[tid - 32] = betas_next[((size_t)t * NB + n) * SPW + (tid - 32)];
    __syncthreads();
    float lz = logZ[n];
    size_t base = (size_t)(t * NB + n) * 1024;
    double local = 0.0;
#pragma unroll
    for (int e = tid; e < 1024; e += 256) {
        int j = e >> 5, i = e & 31;
        float ph = phiT[base + e];
        float lm = ap[i] + ph + bn[j] - lz;
        local += (double)(expf(lm) * ph);
    }
#pragma unroll
    for (int off = 32; off; off >>= 1) local += __shfl_down(local, off);
    __shared__ double wsum[4];
    if ((tid & 63) == 0) wsum[tid >> 6] = local;
    __syncthreads();
    if (tid == 0) atomicAdd(elbo_acc, wsum[0] + wsum[1] + wsum[2] + wsum[3]);
}

// K15: finalize scalar outputs
__global__ void finalize_kernel(const double* __restrict__ elbo_acc,
                                const float* __restrict__ logZ, float* __restrict__ out)
{
    if (threadIdx.x == 0) {
        out[0] = (float)(*elbo_acc);
        float s = 0.f;
        for (int n = 0; n < NB; ++n) s += logZ[n];
        out[1] = s;
    }
}

// ---------------------------------------------------------------------------
extern "C" void kernel_launch(void* const* d_in, const int* in_sizes, int n_in,
                              void* d_out, int out_size, void* d_ws, size_t ws_size,
                              hipStream_t stream) {
    (void)in_sizes; (void)n_in; (void)out_size; (void)ws_size;
    const float* start_emb = (const float*)d_in[0];
    const float* sw1  = (const float*)d_in[1];
    const float* sb1  = (const float*)d_in[2];
    const float* sw2  = (const float*)d_in[3];
    const float* sb2  = (const float*)d_in[4];
    const float* sow  = (const float*)d_in[5];
    const float* sob  = (const float*)d_in[6];
    const float* state_emb = (const float*)d_in[7];
    const float* tw1  = (const float*)d_in[8];
    const float* tb1  = (const float*)d_in[9];
    const float* tw2  = (const float*)d_in[10];
    const float* tb2  = (const float*)d_in[11];
    const float* nsp  = (const float*)d_in[12];
    const float* pre_emb = (const float*)d_in[13];
    const float* ew1  = (const float*)d_in[14];
    const float* eb1  = (const float*)d_in[15];
    const float* ew2  = (const float*)d_in[16];
    const float* eb2  = (const float*)d_in[17];
    const float* eow  = (const float*)d_in[18];
    const float* eob  = (const float*)d_in[19];
    const int*   text = (const int*)d_in[20];
    const int*   w2s  = (const int*)d_in[21];

    float* ws = (float*)d_ws;
    float* TL      = ws + OFF_TL;
    float* res     = ws + OFF_RES;
    float* s_tmp   = ws + OFF_STMP;
    float* startl  = ws + OFF_START;
    float* lse1    = ws + OFF_LSE1;
    float* lse2    = ws + OFF_LSE2;
    unsigned* rmax = (unsigned*)(ws + OFF_RMAX);
    float* rsum    = ws + OFF_RSUM;
    float* den     = ws + OFF_DEN;
    float* logZ    = ws + OFF_LOGZ;
    double* elboA  = (double*)(ws + OFF_ELBO);
    float* ewT     = ws + OFF_EWT;
    float* Lm      = ws + OFF_L;
    float* obs     = ws + OFF_OBS;
    float* phiT    = ws + OFF_PHI;
    float* alph    = ws + OFF_ALPH;
    float* beta    = ws + OFF_BETA;
    float* out     = (float*)d_out;

    init_kernel<<<16, 256, 0, stream>>>(rmax, rsum, elboA);

    // start path
    residual_kernel<<<C_ / 16, 256, 0, stream>>>(start_emb, sw1, sb1, sw2, sb2, res);
    start_head_kernel<<<C_ / 4, 256, 0, stream>>>(res, sow, sob, s_tmp);
    logsoftmax_start_kernel<<<1, 1024, 0, stream>>>(s_tmp, startl);

    // transition path
    residual_kernel<<<C_ / 16, 256, 0, stream>>>(state_emb, tw1, tb1, tw2, tb2, res);
    matmul_nt_kernel<<<dim3(64, 64), 256, 0, stream>>>(res, nsp, TL);
    row_lse_kernel<<<C_, 256, 0, stream>>>(TL, nullptr, lse1, 0);
    row_lse_kernel<<<C_, 256, 0, stream>>>(TL, lse1, lse2, 1);

    // emission path (sparse: only the V*SPW masked entries)
    residual_kernel<<<C_ / 16, 256, 0, stream>>>(pre_emb, ew1, eb1, ew2, eb2, res);
    transpose_kernel<<<dim3(V_ / 32, H_ / 32), 256, 0, stream>>>(eow, ewT);
    em_logits_kernel<<<V_, 256, 0, stream>>>(res, ewT, eob, w2s, Lm);
    row_max_kernel<<<V_ / 8, 256, 0, stream>>>(w2s, Lm, rmax);
    row_sum_kernel<<<V_ / 8, 256, 0, stream>>>(w2s, Lm, rmax, rsum);
    denom_kernel<<<16, 256, 0, stream>>>(rmax, rsum, den);
    obs_kernel<<<(NB * TT * SPW) / 256, 256, 0, stream>>>(text, w2s, Lm, den, obs);

    // phi assembly + scans + outputs
    phi_kernel<<<(TT - 1) * NB, 256, 0, stream>>>(TL, lse1, lse2, obs, startl, text, w2s, phiT);
    scan_kernel<<<2 * NB, 1024, 0, stream>>>(phiT, alph, beta, logZ, out);
    elbo_kernel<<<(TT - 1) * NB, 256, 0, stream>>>(phiT, alph, beta, logZ, elboA);
    finalize_kernel<<<1, 64, 0, stream>>>(elboA, logZ, out);
}